// Round 4
// baseline (368.997 us; speedup 1.0000x reference)
//
#include <hip/hip_runtime.h>
#include <stdint.h>

#define T_STEPS 30
#define BTOT 65536

typedef __bf16 bf16_t;
typedef bf16_t bf16x8 __attribute__((ext_vector_type(8)));
typedef float f32x4 __attribute__((ext_vector_type(4)));
typedef float f32x2 __attribute__((ext_vector_type(2)));

__device__ __forceinline__ f32x2 pk(float x) { return f32x2{x, x}; }
__device__ __forceinline__ f32x2 rcp_pk(f32x2 d) {
    f32x2 r;
    r[0] = __builtin_amdgcn_rcpf(d[0]);
    r[1] = __builtin_amdgcn_rcpf(d[1]);
    return r;
}
// tanh Pade(7,6): tanh(y) ~= y*(135135 + 17325u + 378u^2 + u^3) /
//                           (135135 + 62370u + 3150u^2 + 28u^3),  u = y^2
// |err| <= 1.5e-4 for |y| <= 4.75; for |y| up to 5.75 (our hard bound on
// unclamped gate args) it overshoots by <= +1.3e-3 -- tolerable, no clamp.
__device__ __forceinline__ void tanh_pq(f32x2 y, f32x2& P, f32x2& Q) {
    const f32x2 u = y * y;
    f32x2 p = u + pk(378.0f);
    p = __builtin_elementwise_fma(p, u, pk(17325.0f));
    p = __builtin_elementwise_fma(p, u, pk(135135.0f));
    P = p * y;
    f32x2 q = __builtin_elementwise_fma(u, pk(28.0f), pk(3150.0f));
    q = __builtin_elementwise_fma(q, u, pk(62370.0f));
    Q = __builtin_elementwise_fma(q, u, pk(135135.0f));
}
__device__ __forceinline__ f32x2 clamp_pk(f32x2 y) {   // |c'| is unbounded: clamp
    f32x2 r;
    r[0] = __builtin_amdgcn_fmed3f(y[0], -4.75f, 4.75f);
    r[1] = __builtin_amdgcn_fmed3f(y[1], -4.75f, 4.75f);
    return r;
}

// 8 independent waves per 512-thread block; each wave owns 16 batch rows and
// runs all 3 layers x 30 steps, no barriers after weight staging.
// MFMA 16x16x32 bf16:
//   A (16 batch x 32 k): row = lane&15, k = (lane>>4)*8 + j
//   B: LDS frags, frag[lane] = W[tile*16 + (lane&15)][(lane>>4)*8+j]
//   C/D: col(gate) = lane&15, row(batch) = (lane>>4)*4 + reg   [m89/m91]
// Gate tiles: 0,1=i; 2,3=f; 4,5=g; 6,7=o (PyTorch order).
// Activations: division-free sigmoid-from-tanh, packed f32x2 over the two
// tiles of each gate:  sig(a) = 0.5*(1 + tanh(a/2));  c' and h each merge
// their rational denominators into a single rcp:
//   c' = [(Qf+Pf)*c*Qi*Qg + (Qi+Pi)*Pg*Qf] / (2*Qi*Qg*Qf)
//   h  = (Qo+Po)*Pc / (2*Qo*Qc)
// => 2 rcp + 0 exp per element (was 5 exp + 2 rcp).
template <int LI, bool SAVE>
__device__ __forceinline__ void cell(
    int lane, int lrow, int kgrp,
    const bf16_t* __restrict__ wb,       // laundered LDS weight-fragment base
    const f32x2 (&bsig)[3][3],           // packed 0.5*bias for i,f,o
    const f32x2 (&bg)[3],                // packed bias for g
    bf16x8 ain,                          // A-frag: x or h from layer below
    bf16x8& ah,                          // in: h_{t-1} A-frag ; out: h_t
    f32x2 (&cst)[3][4],                  // fp32 cell state, packed over mt
    f32x2 (&hsave)[4],
    bf16_t* __restrict__ hb)             // wave-private exchange, row stride 40
{
    constexpr int WIH_OFF = ((LI == 0) ? 0 : (LI == 1) ? 2 : 4) * 4096;
    constexpr int WHH_OFF = WIH_OFF + 4096;

    f32x4 z;
    z[0] = 0.0f; z[1] = 0.0f; z[2] = 0.0f; z[3] = 0.0f;
    f32x4 acc[8];
#pragma unroll
    for (int tl = 0; tl < 8; ++tl) {
        bf16x8 bfr = *(const bf16x8*)(wb + WIH_OFF + (tl << 9) + (lane << 3));
        acc[tl] = __builtin_amdgcn_mfma_f32_16x16x32_bf16(ain, bfr, z, 0, 0, 0);
    }
#pragma unroll
    for (int tl = 0; tl < 8; ++tl) {
        bf16x8 bfr = *(const bf16x8*)(wb + WHH_OFF + (tl << 9) + (lane << 3));
        acc[tl] = __builtin_amdgcn_mfma_f32_16x16x32_bf16(ah, bfr, acc[tl], 0, 0, 0);
    }
#pragma unroll
    for (int r = 0; r < 4; ++r) {
        const f32x2 a_i = {acc[0][r], acc[1][r]};
        const f32x2 a_f = {acc[2][r], acc[3][r]};
        const f32x2 a_g = {acc[4][r], acc[5][r]};
        const f32x2 a_o = {acc[6][r], acc[7][r]};
        // sigmoid args: y = 0.5*a + 0.5*b (bias free in the fma); g: y = a + b
        const f32x2 yi = __builtin_elementwise_fma(a_i, pk(0.5f), bsig[LI][0]);
        const f32x2 yf = __builtin_elementwise_fma(a_f, pk(0.5f), bsig[LI][1]);
        const f32x2 yg = a_g + bg[LI];
        const f32x2 yo = __builtin_elementwise_fma(a_o, pk(0.5f), bsig[LI][2]);
        f32x2 Pi, Qi, Pf, Qf, Pg, Qg, Po, Qo;
        tanh_pq(yi, Pi, Qi);
        tanh_pq(yf, Pf, Qf);
        tanh_pq(yg, Pg, Qg);
        tanh_pq(yo, Po, Qo);
        const f32x2 sf  = Qf + Pf;
        const f32x2 si  = Qi + Pi;
        const f32x2 qig = Qi * Qg;
        const f32x2 m1  = sf * cst[LI][r];
        const f32x2 m2  = (si * Pg) * Qf;
        const f32x2 N   = __builtin_elementwise_fma(m1, qig, m2);
        const f32x2 D2  = (qig * Qf) * pk(2.0f);
        const f32x2 cc  = N * rcp_pk(D2);
        cst[LI][r] = cc;
        f32x2 Pc, Qc;
        tanh_pq(clamp_pk(cc), Pc, Qc);
        const f32x2 hn  = (Qo + Po) * Pc;
        const f32x2 hd2 = (Qo * Qc) * pk(2.0f);
        const f32x2 hv  = hn * rcp_pk(hd2);
        if (SAVE) hsave[r] = hv;
        hb[(kgrp * 4 + r) * 40 + lrow]      = (bf16_t)hv[0];   // mt=0
        hb[(kgrp * 4 + r) * 40 + 16 + lrow] = (bf16_t)hv[1];   // mt=1
    }
    // reload own h_t as A-frag (intra-wave, in-order DS pipe: no barrier)
    ah = *(const bf16x8*)(hb + lrow * 40 + (kgrp << 3));
}

__global__ __launch_bounds__(512, 4) void lstm3_fused(
    const float* __restrict__ X,
    const float* __restrict__ Wih0, const float* __restrict__ Whh0,
    const float* __restrict__ bih0, const float* __restrict__ bhh0,
    const float* __restrict__ Wih1, const float* __restrict__ Whh1,
    const float* __restrict__ bih1, const float* __restrict__ bhh1,
    const float* __restrict__ Wih2, const float* __restrict__ Whh2,
    const float* __restrict__ bih2, const float* __restrict__ bhh2,
    const float* __restrict__ W1, const float* __restrict__ b1,
    const float* __restrict__ W2, const float* __restrict__ b2,
    float* __restrict__ out)
{
    __shared__ alignas(16) bf16_t wfrag[6 * 4096];   // 48 KB, shared by 8 waves
    __shared__ float bias_s[3][128];
    __shared__ alignas(16) bf16_t hbuf[8][16 * 40];  // per-wave, stride 40
    __shared__ float hfin[8][16][33];                // +1 pad: head reads clean

    const int tid = threadIdx.x;

    auto stage = [&](int mat, const float* __restrict__ w, int K) {
        for (int p = tid; p < 4096; p += 512) {
            const int tile = p >> 9;
            const int r = p & 511;
            const int ln = r >> 3;
            const int j = r & 7;
            const int k = ((ln >> 4) << 3) + j;
            const int n = (tile << 4) + (ln & 15);
            const float v = (k < K) ? w[n * K + k] : 0.0f;
            wfrag[mat * 4096 + p] = (bf16_t)v;
        }
    };
    stage(0, Wih0, 3);
    stage(1, Whh0, 32);
    stage(2, Wih1, 32);
    stage(3, Whh1, 32);
    stage(4, Wih2, 32);
    stage(5, Whh2, 32);
    for (int p = tid; p < 384; p += 512) {
        const int l = p >> 7, n = p & 127;
        float v;
        if (l == 0)      v = bih0[n] + bhh0[n];
        else if (l == 1) v = bih1[n] + bhh1[n];
        else             v = bih2[n] + bhh2[n];
        bias_s[l][n] = v;
    }
    __syncthreads();

    const int wave = tid >> 6;
    const int lane = tid & 63;
    const int lrow = lane & 15;
    const int kgrp = lane >> 4;
    const int b0   = blockIdx.x * 128 + wave * 16;

    // packed biases: gate g's two tiles -> one f32x2; sigmoid biases pre-halved
    f32x2 bsig[3][3];
    f32x2 bg[3];
#pragma unroll
    for (int l = 0; l < 3; ++l) {
#pragma unroll
        for (int g = 0; g < 3; ++g) {
            const int base = (g == 2) ? 96 : g * 32;   // i, f, o blocks
            bsig[l][g] = f32x2{0.5f * bias_s[l][base + lrow],
                               0.5f * bias_s[l][base + 16 + lrow]};
        }
        bg[l] = f32x2{bias_s[l][64 + lrow], bias_s[l][80 + lrow]};
    }

    f32x2 cst[3][4];
    f32x2 h2keep[4];
#pragma unroll
    for (int l = 0; l < 3; ++l)
#pragma unroll
        for (int r = 0; r < 4; ++r) cst[l][r] = pk(0.0f);
#pragma unroll
    for (int r = 0; r < 4; ++r) h2keep[r] = pk(0.0f);

    bf16x8 ah0, ah1, ah2;
#pragma unroll
    for (int j = 0; j < 8; ++j) {
        ah0[j] = (bf16_t)0.0f; ah1[j] = (bf16_t)0.0f; ah2[j] = (bf16_t)0.0f;
    }

    bf16_t* hb = &hbuf[wave][0];

    const float* xlane = X + (size_t)(b0 + lrow) * (T_STEPS * 3);
    float cx0 = xlane[0], cx1 = xlane[1], cx2 = xlane[2];

    for (int t = 0; t < T_STEPS; ++t) {
        const int tn = (t < T_STEPS - 1) ? (t + 1) : (T_STEPS - 1);
        const float nx0 = xlane[tn * 3 + 0];
        const float nx1 = xlane[tn * 3 + 1];
        const float nx2 = xlane[tn * 3 + 2];

        // launder LDS base each iteration so LICM can't hoist 48 weight frags
        unsigned lz = 0;
        asm volatile("" : "+v"(lz));
        const bf16_t* wbt = wfrag + lz;

        bf16x8 ax;
#pragma unroll
        for (int j = 0; j < 8; ++j) ax[j] = (bf16_t)0.0f;
        if (kgrp == 0) { ax[0] = (bf16_t)cx0; ax[1] = (bf16_t)cx1; ax[2] = (bf16_t)cx2; }

        cell<0, false>(lane, lrow, kgrp, wbt, bsig, bg, ax,  ah0, cst, h2keep, hb);
        cell<1, false>(lane, lrow, kgrp, wbt, bsig, bg, ah0, ah1, cst, h2keep, hb);
        cell<2, true >(lane, lrow, kgrp, wbt, bsig, bg, ah1, ah2, cst, h2keep, hb);

        cx0 = nx0; cx1 = nx1; cx2 = nx2;
    }

    // ---- head: out = (h2 @ W1^T + b1) @ W2^T + b2, fp32 ----
#pragma unroll
    for (int r = 0; r < 4; ++r) {
        hfin[wave][kgrp * 4 + r][lrow]      = h2keep[r][0];
        hfin[wave][kgrp * 4 + r][16 + lrow] = h2keep[r][1];
    }

    if (lane < 16) {
        float hv[32];
#pragma unroll
        for (int k = 0; k < 32; ++k) hv[k] = hfin[wave][lane][k];
        float y1[16];
#pragma unroll
        for (int o = 0; o < 16; ++o) {
            float a = b1[o];
#pragma unroll
            for (int k = 0; k < 32; ++k) a += hv[k] * W1[o * 32 + k];
            y1[o] = a;
        }
        const int b = b0 + lane;
#pragma unroll
        for (int q = 0; q < 7; ++q) {
            float a = b2[q];
#pragma unroll
            for (int o = 0; o < 16; ++o) a += y1[o] * W2[q * 16 + o];
            out[b * 7 + q] = a;
        }
    }
}

extern "C" void kernel_launch(void* const* d_in, const int* in_sizes, int n_in,
                              void* d_out, int out_size, void* d_ws, size_t ws_size,
                              hipStream_t stream) {
    (void)in_sizes; (void)n_in; (void)d_ws; (void)ws_size; (void)out_size;
    const float* X    = (const float*)d_in[0];
    const float* Wih0 = (const float*)d_in[1];
    const float* Whh0 = (const float*)d_in[2];
    const float* bih0 = (const float*)d_in[3];
    const float* bhh0 = (const float*)d_in[4];
    const float* Wih1 = (const float*)d_in[5];
    const float* Whh1 = (const float*)d_in[6];
    const float* bih1 = (const float*)d_in[7];
    const float* bhh1 = (const float*)d_in[8];
    const float* Wih2 = (const float*)d_in[9];
    const float* Whh2 = (const float*)d_in[10];
    const float* bih2 = (const float*)d_in[11];
    const float* bhh2 = (const float*)d_in[12];
    const float* W1   = (const float*)d_in[13];
    const float* b1   = (const float*)d_in[14];
    const float* W2   = (const float*)d_in[15];
    const float* b2   = (const float*)d_in[16];
    float* out = (float*)d_out;

    dim3 grid(BTOT / 128), block(512);
    hipLaunchKernelGGL(lstm3_fused, grid, block, 0, stream,
                       X, Wih0, Whh0, bih0, bhh0, Wih1, Whh1, bih1, bhh1,
                       Wih2, Whh2, bih2, bhh2, W1, b1, W2, b2, out);
}

// Round 6
// 319.183 us; speedup vs baseline: 1.1561x; 1.1561x over previous
//
#include <hip/hip_runtime.h>
#include <stdint.h>

#define T_STEPS 30
#define BTOT 65536
#define L2E 1.4426950408889634f

typedef __bf16 bf16_t;
typedef bf16_t bf16x8 __attribute__((ext_vector_type(8)));
typedef float f32x4 __attribute__((ext_vector_type(4)));
typedef float f32x2 __attribute__((ext_vector_type(2)));
typedef uint32_t u32x4 __attribute__((ext_vector_type(4)));

__device__ __forceinline__ float exp2_fast(float x) {
#if __has_builtin(__builtin_amdgcn_exp2f)
    return __builtin_amdgcn_exp2f(x);
#else
    return __expf(x * 0.6931471805599453f);
#endif
}
__device__ __forceinline__ float rcp_fast(float x) {
    return __builtin_amdgcn_rcpf(x);
}

// 8 independent waves per 512-thread block; each wave owns 16 batch rows and
// runs all 3 layers x 30 steps, no barriers after weight staging (R3 skeleton).
// MFMA 16x16x32 bf16:
//   A (16 batch x 32 k): row = lane&15, k = (lane>>4)*8 + j
//   B: LDS frags (Wih0,Whh0,Wih1,Whh1,Wih2) / VGPR frags (Whh2)
//   C/D: col(gate) = lane&15, row(batch) = (lane>>4)*4 + reg   [m89/m91]
// Gate tiles: 0,1=i; 2,3=f; 4,5=g; 6,7=o (PyTorch order).
// Pointwise: exp-form, 5 exp2 + 2 rcp per element (proven absmax 1.95e-3):
//   A=e^{-ai},F=e^{-af},B=e^{-2ag},O=e^{-ao}  (bias pre-folded, exp2 form)
//   c' = (c*(1+A)(1+B) + (1-B)(1+F)) / ((1+F)(1+A)(1+B))
//   h  = (1-C)/((1+O)(1+C)),  C=e^{-2c'}
// h exchange: fp32 LDS [16][38] (b64-aligned rows, ~2-way banks vs old 8-way),
// readback packs to bf16 A-frag via v_cvt_pk_bf16_f32.
template <int LI>
__device__ __forceinline__ void cell(
    int lane, int lrow, int kgrp,
    const bf16_t* __restrict__ wb,       // laundered LDS weight-fragment base
    const bf16x8* __restrict__ whh2,     // register-cached Whh2 (LI==2 only)
    const float (&bsL)[8],               // this layer's pre-scaled biases
    bf16x8 ain,                          // A-frag: x or h from layer below
    bf16x8& ah,                          // in: h_{t-1} A-frag ; out: h_t
    float (&cst)[2][4],                  // fp32 cell state
    float* __restrict__ hb)              // wave-private fp32 h buffer, stride 38
{
    constexpr int WIH_OFF = ((LI == 0) ? 0 : (LI == 1) ? 2 : 4) * 4096;
    constexpr int WHH_OFF = ((LI == 0) ? 1 : 3) * 4096;   // LI==2 uses regs

    f32x4 z;
    z[0] = 0.0f; z[1] = 0.0f; z[2] = 0.0f; z[3] = 0.0f;
    f32x4 acc[8];
#pragma unroll
    for (int tl = 0; tl < 8; ++tl) {
        bf16x8 bfr = *(const bf16x8*)(wb + WIH_OFF + (tl << 9) + (lane << 3));
        acc[tl] = __builtin_amdgcn_mfma_f32_16x16x32_bf16(ain, bfr, z, 0, 0, 0);
    }
#pragma unroll
    for (int tl = 0; tl < 8; ++tl) {
        bf16x8 bfr;
        if constexpr (LI == 2) {
            bfr = whh2[tl];
        } else {
            bfr = *(const bf16x8*)(wb + WHH_OFF + (tl << 9) + (lane << 3));
        }
        acc[tl] = __builtin_amdgcn_mfma_f32_16x16x32_bf16(ah, bfr, acc[tl], 0, 0, 0);
    }
#pragma unroll
    for (int mt = 0; mt < 2; ++mt) {
#pragma unroll
        for (int r = 0; r < 4; ++r) {
            const float Ae = exp2_fast(acc[0 + mt][r] * (-L2E) + bsL[0 + mt]);
            const float Fe = exp2_fast(acc[2 + mt][r] * (-L2E) + bsL[2 + mt]);
            const float Be = exp2_fast(acc[4 + mt][r] * (-2.0f * L2E) + bsL[4 + mt]);
            const float Oe = exp2_fast(acc[6 + mt][r] * (-L2E) + bsL[6 + mt]);
            const float pA = 1.0f + Ae, pF = 1.0f + Fe, pB = 1.0f + Be, pO = 1.0f + Oe;
            const float nB = 1.0f - Be;
            const float t1 = pA * pB;
            const float D  = t1 * pF;
            const float N  = __builtin_fmaf(cst[mt][r], t1, nB * pF);
            const float cc = N * rcp_fast(D);
            cst[mt][r] = cc;
            const float Ce = exp2_fast(cc * (-2.0f * L2E));
            const float hv = (1.0f - Ce) * rcp_fast(pO * (1.0f + Ce));
            hb[(kgrp * 4 + r) * 38 + mt * 16 + lrow] = hv;   // fp32, no cvt
        }
    }
    // reload own h_t as A-frag: 4x ds_read_b64 (fp32) + 4x cvt_pk -> bf16x8.
    // Same-wave DS is in-order: reads see the stores above, no barrier.
    const float* rb = hb + lrow * 38 + (kgrp << 3);
    const f32x2 w0 = *(const f32x2*)(rb + 0);
    const f32x2 w1 = *(const f32x2*)(rb + 2);
    const f32x2 w2 = *(const f32x2*)(rb + 4);
    const f32x2 w3 = *(const f32x2*)(rb + 6);
    uint32_t d0, d1, d2, d3;
    asm("v_cvt_pk_bf16_f32 %0, %1, %2" : "=v"(d0) : "v"(w0[0]), "v"(w0[1]));
    asm("v_cvt_pk_bf16_f32 %0, %1, %2" : "=v"(d1) : "v"(w1[0]), "v"(w1[1]));
    asm("v_cvt_pk_bf16_f32 %0, %1, %2" : "=v"(d2) : "v"(w2[0]), "v"(w2[1]));
    asm("v_cvt_pk_bf16_f32 %0, %1, %2" : "=v"(d3) : "v"(w3[0]), "v"(w3[1]));
    u32x4 u;
    u[0] = d0; u[1] = d1; u[2] = d2; u[3] = d3;
    ah = __builtin_bit_cast(bf16x8, u);
}

__global__ __launch_bounds__(512, 4) void lstm3_fused(
    const float* __restrict__ X,
    const float* __restrict__ Wih0, const float* __restrict__ Whh0,
    const float* __restrict__ bih0, const float* __restrict__ bhh0,
    const float* __restrict__ Wih1, const float* __restrict__ Whh1,
    const float* __restrict__ bih1, const float* __restrict__ bhh1,
    const float* __restrict__ Wih2, const float* __restrict__ Whh2,
    const float* __restrict__ bih2, const float* __restrict__ bhh2,
    const float* __restrict__ W1, const float* __restrict__ b1,
    const float* __restrict__ W2, const float* __restrict__ b2,
    float* __restrict__ out)
{
    __shared__ alignas(16) bf16_t wfrag[5 * 4096];      // 40 KB: ih0,hh0,ih1,hh1,ih2
    __shared__ float bias_s[3][128];                    // 1.5 KB
    __shared__ alignas(16) float hbuf32[8][16 * 38];    // 19 KB: fp32 h, stride 38

    const int tid = threadIdx.x;

    auto stage = [&](int mat, const float* __restrict__ w, int K) {
        for (int p = tid; p < 4096; p += 512) {
            const int tile = p >> 9;
            const int r = p & 511;
            const int ln = r >> 3;
            const int j = r & 7;
            const int k = ((ln >> 4) << 3) + j;
            const int n = (tile << 4) + (ln & 15);
            const float v = (k < K) ? w[n * K + k] : 0.0f;
            wfrag[mat * 4096 + p] = (bf16_t)v;
        }
    };
    stage(0, Wih0, 3);
    stage(1, Whh0, 32);
    stage(2, Wih1, 32);
    stage(3, Whh1, 32);
    stage(4, Wih2, 32);
    for (int p = tid; p < 384; p += 512) {
        const int l = p >> 7, n = p & 127;
        float v;
        if (l == 0)      v = bih0[n] + bhh0[n];
        else if (l == 1) v = bih1[n] + bhh1[n];
        else             v = bih2[n] + bhh2[n];
        bias_s[l][n] = v;
    }
    __syncthreads();

    const int wave = tid >> 6;
    const int lane = tid & 63;
    const int lrow = lane & 15;
    const int kgrp = lane >> 4;
    const int b0   = blockIdx.x * 128 + wave * 16;

    // Whh2 B-fragments -> registers (32 VGPRs, built once from global; L2-hot)
    bf16x8 whh2[8];
#pragma unroll
    for (int tl = 0; tl < 8; ++tl) {
        const int n = tl * 16 + lrow;
        const float* q = Whh2 + n * 32 + kgrp * 8;
        bf16x8 f;
#pragma unroll
        for (int j = 0; j < 8; ++j) f[j] = (bf16_t)q[j];
        whh2[tl] = f;
    }

    // de-phase-lock the 4 waves/SIMD: stagger starts by ~0/256/512/768 cycles
    switch (wave & 3) {
        case 1: __builtin_amdgcn_s_sleep(4);  break;
        case 2: __builtin_amdgcn_s_sleep(8);  break;
        case 3: __builtin_amdgcn_s_sleep(12); break;
        default: break;
    }

    // pre-scaled biases: -L2E*b for sigmoid tiles, -2*L2E*b for g tiles
    float bs[3][8];
#pragma unroll
    for (int l = 0; l < 3; ++l)
#pragma unroll
        for (int tl = 0; tl < 8; ++tl)
            bs[l][tl] = bias_s[l][tl * 16 + lrow] *
                        (((tl >> 1) == 2) ? (-2.0f * L2E) : (-L2E));

    float cst[3][2][4];
#pragma unroll
    for (int l = 0; l < 3; ++l)
#pragma unroll
        for (int mt = 0; mt < 2; ++mt)
#pragma unroll
            for (int r = 0; r < 4; ++r) cst[l][mt][r] = 0.0f;

    bf16x8 ah0, ah1, ah2;
#pragma unroll
    for (int j = 0; j < 8; ++j) {
        ah0[j] = (bf16_t)0.0f; ah1[j] = (bf16_t)0.0f; ah2[j] = (bf16_t)0.0f;
    }

    float* hb = &hbuf32[wave][0];

    const float* xlane = X + (size_t)(b0 + lrow) * (T_STEPS * 3);
    float cx0 = xlane[0], cx1 = xlane[1], cx2 = xlane[2];

    for (int t = 0; t < T_STEPS; ++t) {
        const int tn = (t < T_STEPS - 1) ? (t + 1) : (T_STEPS - 1);
        const float nx0 = xlane[tn * 3 + 0];
        const float nx1 = xlane[tn * 3 + 1];
        const float nx2 = xlane[tn * 3 + 2];

        // launder LDS base each iteration so LICM can't hoist 40 weight frags
        unsigned lz = 0;
        asm volatile("" : "+v"(lz));
        const bf16_t* wbt = wfrag + lz;

        bf16x8 ax;
#pragma unroll
        for (int j = 0; j < 8; ++j) ax[j] = (bf16_t)0.0f;
        if (kgrp == 0) { ax[0] = (bf16_t)cx0; ax[1] = (bf16_t)cx1; ax[2] = (bf16_t)cx2; }

        cell<0>(lane, lrow, kgrp, wbt, whh2, bs[0], ax,  ah0, cst[0], hb);
        cell<1>(lane, lrow, kgrp, wbt, whh2, bs[1], ah0, ah1, cst[1], hb);
        cell<2>(lane, lrow, kgrp, wbt, whh2, bs[2], ah1, ah2, cst[2], hb);

        cx0 = nx0; cx1 = nx1; cx2 = nx2;
    }

    // ---- head: out = (h2 @ W1^T + b1) @ W2^T + b2, fp32.
    // hbuf32 holds the final h2 (fp32) from the last cell<2> -- read directly.
    if (lane < 16) {
        const float* hrow = hb + lane * 38;
        float hv[32];
#pragma unroll
        for (int k = 0; k < 32; ++k) hv[k] = hrow[k];
        float y1[16];
#pragma unroll
        for (int o = 0; o < 16; ++o) {
            float a = b1[o];
#pragma unroll
            for (int k = 0; k < 32; ++k) a += hv[k] * W1[o * 32 + k];
            y1[o] = a;
        }
        const int b = b0 + lane;
#pragma unroll
        for (int q = 0; q < 7; ++q) {
            float a = b2[q];
#pragma unroll
            for (int o = 0; o < 16; ++o) a += y1[o] * W2[q * 16 + o];
            out[b * 7 + q] = a;
        }
    }
}

extern "C" void kernel_launch(void* const* d_in, const int* in_sizes, int n_in,
                              void* d_out, int out_size, void* d_ws, size_t ws_size,
                              hipStream_t stream) {
    (void)in_sizes; (void)n_in; (void)d_ws; (void)ws_size; (void)out_size;
    const float* X    = (const float*)d_in[0];
    const float* Wih0 = (const float*)d_in[1];
    const float* Whh0 = (const float*)d_in[2];
    const float* bih0 = (const float*)d_in[3];
    const float* bhh0 = (const float*)d_in[4];
    const float* Wih1 = (const float*)d_in[5];
    const float* Whh1 = (const float*)d_in[6];
    const float* bih1 = (const float*)d_in[7];
    const float* bhh1 = (const float*)d_in[8];
    const float* Wih2 = (const float*)d_in[9];
    const float* Whh2 = (const float*)d_in[10];
    const float* bih2 = (const float*)d_in[11];
    const float* bhh2 = (const float*)d_in[12];
    const float* W1   = (const float*)d_in[13];
    const float* b1   = (const float*)d_in[14];
    const float* W2   = (const float*)d_in[15];
    const float* b2   = (const float*)d_in[16];
    float* out = (float*)d_out;

    dim3 grid(BTOT / 128), block(512);
    hipLaunchKernelGGL(lstm3_fused, grid, block, 0, stream,
                       X, Wih0, Whh0, bih0, bhh0, Wih1, Whh1, bih1, bhh1,
                       Wih2, Whh2, bih2, bhh2, W1, b1, W2, b2, out);
}

// Round 7
// 312.610 us; speedup vs baseline: 1.1804x; 1.0210x over previous
//
#include <hip/hip_runtime.h>
#include <stdint.h>

#define T_STEPS 30
#define BTOT 65536
#define L2E 1.4426950408889634f

typedef __bf16 bf16_t;
typedef bf16_t bf16x8 __attribute__((ext_vector_type(8)));
typedef float f32x4 __attribute__((ext_vector_type(4)));
typedef uint32_t u32x2 __attribute__((ext_vector_type(2)));
typedef uint32_t u32x4 __attribute__((ext_vector_type(4)));

__device__ __forceinline__ float exp2_fast(float x) {
#if __has_builtin(__builtin_amdgcn_exp2f)
    return __builtin_amdgcn_exp2f(x);
#else
    return __expf(x * 0.6931471805599453f);
#endif
}
__device__ __forceinline__ float rcp_fast(float x) {
    return __builtin_amdgcn_rcpf(x);
}

// Gate-split wave pairs: 512-thread blocks = 8 waves = 4 pairs; each pair owns
// 16 batch rows; wave q (=wave&1) of a pair computes gate tiles {q,2+q,4+q,6+q}
// (its 16 hidden units): 8 MFMAs + 28 trans per cell instead of 16 + 56.
// Halves exchange h via per-pair double-buffered LDS + 1 barrier/cell.
// Aggregate trans/MFMA/LDS-weight traffic unchanged; waves double: 8192 waves
// -> 6 waves/SIMD (3 blocks/CU) for better trans-unit phase overlap.
//
// MFMA 16x16x32 bf16 (layouts as proven R3):
//   A: row = lane&15 (batch), k = (lane>>4)*8 + j
//   B frag[lane] = W[16*tile + (lane&15)][(lane>>4)*8 + j]
//   C/D: col(gate) = lane&15, row(batch) = (lane>>4)*4 + reg
// Tile 2G+q covers gate-class G (0=i,1=f,2=g,3=o), gate n = 32G + 16q + lrow.
// Pointwise (proven exp-form, absmax 1.95e-3): 5 exp2 + 2 rcp per element.
template <int MIH, int MHH, bool X0>
__device__ __forceinline__ void cellS(
    int lane, int lrow, int kgrp, int q,
    const bf16_t* __restrict__ wb,     // laundered LDS weight-fragment base
    const bf16_t* __restrict__ w0,     // compact Wih0 base (X0 only)
    const float (&bsL)[4],             // this layer's pre-scaled biases
    bf16x8 ain,                        // A-frag: x or h from layer below
    bf16x8& ah,                        // in: h_{t-1}; out: h_t (full 32-k frag)
    float (&cst)[4],                   // fp32 cell state (4 batch rows)
    float (&h2k)[4], bool sv,          // save slot for final h2 (fp32)
    bf16_t* __restrict__ hbw)          // pair's exchange buffer (this cell's)
{
    f32x4 z;
    z[0] = 0.0f; z[1] = 0.0f; z[2] = 0.0f; z[3] = 0.0f;
    f32x4 acc[4];
#pragma unroll
    for (int G = 0; G < 4; ++G) {
        const int tile = 2 * G + q;
        bf16x8 fi;
        if constexpr (X0) {
            // Wih0 compact: 8B (k=0..2 + zero pad) for kgrp==0 lanes only
            u32x2 u;
            u[0] = 0u; u[1] = 0u;
            if (kgrp == 0) u = *(const u32x2*)(w0 + (tile * 16 + lrow) * 4);
            u32x4 uu;
            uu[0] = u[0]; uu[1] = u[1]; uu[2] = 0u; uu[3] = 0u;
            fi = __builtin_bit_cast(bf16x8, uu);
        } else {
            fi = *(const bf16x8*)(wb + MIH * 4096 + (tile << 9) + (lane << 3));
        }
        acc[G] = __builtin_amdgcn_mfma_f32_16x16x32_bf16(ain, fi, z, 0, 0, 0);
    }
#pragma unroll
    for (int G = 0; G < 4; ++G) {
        const int tile = 2 * G + q;
        bf16x8 fh = *(const bf16x8*)(wb + MHH * 4096 + (tile << 9) + (lane << 3));
        acc[G] = __builtin_amdgcn_mfma_f32_16x16x32_bf16(ah, fh, acc[G], 0, 0, 0);
    }
#pragma unroll
    for (int r = 0; r < 4; ++r) {
        const float Ae = exp2_fast(acc[0][r] * (-L2E) + bsL[0]);
        const float Fe = exp2_fast(acc[1][r] * (-L2E) + bsL[1]);
        const float Be = exp2_fast(acc[2][r] * (-2.0f * L2E) + bsL[2]);
        const float Oe = exp2_fast(acc[3][r] * (-L2E) + bsL[3]);
        const float pA = 1.0f + Ae, pF = 1.0f + Fe, pB = 1.0f + Be, pO = 1.0f + Oe;
        const float nB = 1.0f - Be;
        const float t1 = pA * pB;
        const float D  = t1 * pF;
        const float N  = __builtin_fmaf(cst[r], t1, nB * pF);
        const float cc = N * rcp_fast(D);
        cst[r] = cc;
        const float Ce = exp2_fast(cc * (-2.0f * L2E));
        const float hv = (1.0f - Ce) * rcp_fast(pO * (1.0f + Ce));
        if (sv) h2k[r] = hv;
        hbw[(kgrp * 4 + r) * 40 + 16 * q + lrow] = (bf16_t)hv;
    }
    __syncthreads();   // pair halves (and whole block) exchange h
    ah = *(const bf16x8*)(hbw + lrow * 40 + (kgrp << 3));
}

__global__ __launch_bounds__(512, 6) void lstm3_split(
    const float* __restrict__ X,
    const float* __restrict__ Wih0, const float* __restrict__ Whh0,
    const float* __restrict__ bih0, const float* __restrict__ bhh0,
    const float* __restrict__ Wih1, const float* __restrict__ Whh1,
    const float* __restrict__ bih1, const float* __restrict__ bhh1,
    const float* __restrict__ Wih2, const float* __restrict__ Whh2,
    const float* __restrict__ bih2, const float* __restrict__ bhh2,
    const float* __restrict__ W1, const float* __restrict__ b1,
    const float* __restrict__ W2, const float* __restrict__ b2,
    float* __restrict__ out)
{
    __shared__ alignas(16) bf16_t wfrag[5 * 4096];       // 40 KB: hh0,ih1,hh1,ih2,hh2
    __shared__ alignas(8)  bf16_t w0c[512];              // 1 KB: Wih0 compact
    __shared__ alignas(16) bf16_t hxch[4][2][16 * 40];   // 10 KB: per-pair h dbuf

    const int tid = threadIdx.x;

    auto stage = [&](int mat, const float* __restrict__ w) {
        for (int p = tid; p < 4096; p += 512) {
            const int tile = p >> 9;
            const int r = p & 511;
            const int ln = r >> 3;
            const int j = r & 7;
            const int k = ((ln >> 4) << 3) + j;
            const int n = (tile << 4) + (ln & 15);
            wfrag[mat * 4096 + p] = (bf16_t)w[n * 32 + k];
        }
    };
    stage(0, Whh0);
    stage(1, Wih1);
    stage(2, Whh1);
    stage(3, Wih2);
    stage(4, Whh2);
    {   // Wih0 compact: [tile][lrow][4] (k = 0..2, slot 3 = 0)
        const int p = tid;
        if (p < 512) {
            const int t8 = p >> 6;
            const int lr = (p >> 2) & 15;
            const int k  = p & 3;
            w0c[p] = (k < 3) ? (bf16_t)Wih0[(t8 * 16 + lr) * 3 + k] : (bf16_t)(0.0f);
        }
    }
    __syncthreads();

    const int wave = tid >> 6;
    const int lane = tid & 63;
    const int pair = wave >> 1;
    const int q    = wave & 1;
    const int lrow = lane & 15;
    const int kgrp = lane >> 4;
    const int b0   = blockIdx.x * 64 + pair * 16;

    // biases from global (one-time, L2-hot): bs[l][G], sigmoid pre-scaled -L2E,
    // g pre-scaled -2*L2E, at gate n = 32G + 16q + lrow
    float bs[3][4];
#pragma unroll
    for (int G = 0; G < 4; ++G) {
        const int n = 32 * G + 16 * q + lrow;
        const float s = (G == 2) ? (-2.0f * L2E) : (-L2E);
        bs[0][G] = (bih0[n] + bhh0[n]) * s;
        bs[1][G] = (bih1[n] + bhh1[n]) * s;
        bs[2][G] = (bih2[n] + bhh2[n]) * s;
    }

    float cst[3][4];
    float h2k[4];
#pragma unroll
    for (int l = 0; l < 3; ++l)
#pragma unroll
        for (int r = 0; r < 4; ++r) cst[l][r] = 0.0f;
#pragma unroll
    for (int r = 0; r < 4; ++r) h2k[r] = 0.0f;

    bf16x8 ah0, ah1, ah2;
#pragma unroll
    for (int j = 0; j < 8; ++j) {
        ah0[j] = (bf16_t)0.0f; ah1[j] = (bf16_t)0.0f; ah2[j] = (bf16_t)0.0f;
    }

    const float* xlane = X + (size_t)(b0 + lrow) * (T_STEPS * 3);
    float cx0 = xlane[0], cx1 = xlane[1], cx2 = xlane[2];

    int buf = 0;
    for (int t = 0; t < T_STEPS; ++t) {
        const int tn = (t < T_STEPS - 1) ? (t + 1) : (T_STEPS - 1);
        const float nx0 = xlane[tn * 3 + 0];
        const float nx1 = xlane[tn * 3 + 1];
        const float nx2 = xlane[tn * 3 + 2];

        // launder LDS weight base: blocks LICM from hoisting frag loads
        unsigned lz = 0;
        asm volatile("" : "+v"(lz));
        const bf16_t* wbt = wfrag + lz;
        const bf16_t* w0t = w0c + lz;

        bf16x8 ax;
#pragma unroll
        for (int j = 0; j < 8; ++j) ax[j] = (bf16_t)0.0f;
        if (kgrp == 0) { ax[0] = (bf16_t)cx0; ax[1] = (bf16_t)cx1; ax[2] = (bf16_t)cx2; }

        const bool sv = (t == T_STEPS - 1);
        cellS<0, 0, true >(lane, lrow, kgrp, q, wbt, w0t, bs[0], ax,  ah0,
                           cst[0], h2k, false, &hxch[pair][buf][0]);
        buf ^= 1;
        cellS<1, 2, false>(lane, lrow, kgrp, q, wbt, w0t, bs[1], ah0, ah1,
                           cst[1], h2k, false, &hxch[pair][buf][0]);
        buf ^= 1;
        cellS<3, 4, false>(lane, lrow, kgrp, q, wbt, w0t, bs[2], ah1, ah2,
                           cst[2], h2k, sv,    &hxch[pair][buf][0]);
        buf ^= 1;

        cx0 = nx0; cx1 = nx1; cx2 = nx2;
    }

    // ---- head: out = (h2 @ W1^T + b1) @ W2^T + b2, fp32 ----
    // Reuse wfrag as fp32 hfin[pair][16][33] (all weight reads are done:
    // every wave passed the final cell's internal barrier after its last MFMA).
    float* hf = (float*)wfrag;
    const int hfo = pair * 528;
#pragma unroll
    for (int r = 0; r < 4; ++r)
        hf[hfo + (kgrp * 4 + r) * 33 + 16 * q + lrow] = h2k[r];
    __syncthreads();

    if (q == 0 && lane < 16) {
        float hv[32];
#pragma unroll
        for (int k = 0; k < 32; ++k) hv[k] = hf[hfo + lane * 33 + k];
        float y1[16];
#pragma unroll
        for (int o = 0; o < 16; ++o) {
            float a = b1[o];
#pragma unroll
            for (int k = 0; k < 32; ++k) a += hv[k] * W1[o * 32 + k];
            y1[o] = a;
        }
        const int b = b0 + lane;
#pragma unroll
        for (int oc = 0; oc < 7; ++oc) {
            float a = b2[oc];
#pragma unroll
            for (int o = 0; o < 16; ++o) a += y1[o] * W2[oc * 16 + o];
            out[b * 7 + oc] = a;
        }
    }
}

extern "C" void kernel_launch(void* const* d_in, const int* in_sizes, int n_in,
                              void* d_out, int out_size, void* d_ws, size_t ws_size,
                              hipStream_t stream) {
    (void)in_sizes; (void)n_in; (void)d_ws; (void)ws_size; (void)out_size;
    const float* X    = (const float*)d_in[0];
    const float* Wih0 = (const float*)d_in[1];
    const float* Whh0 = (const float*)d_in[2];
    const float* bih0 = (const float*)d_in[3];
    const float* bhh0 = (const float*)d_in[4];
    const float* Wih1 = (const float*)d_in[5];
    const float* Whh1 = (const float*)d_in[6];
    const float* bih1 = (const float*)d_in[7];
    const float* bhh1 = (const float*)d_in[8];
    const float* Wih2 = (const float*)d_in[9];
    const float* Whh2 = (const float*)d_in[10];
    const float* bih2 = (const float*)d_in[11];
    const float* bhh2 = (const float*)d_in[12];
    const float* W1   = (const float*)d_in[13];
    const float* b1   = (const float*)d_in[14];
    const float* W2   = (const float*)d_in[15];
    const float* b2   = (const float*)d_in[16];
    float* out = (float*)d_out;

    dim3 grid(BTOT / 64), block(512);
    hipLaunchKernelGGL(lstm3_split, grid, block, 0, stream,
                       X, Wih0, Whh0, bih0, bhh0, Wih1, Whh1, bih1, bhh1,
                       Wih2, Whh2, bih2, bhh2, W1, b1, W2, b2, out);
}